// Round 19
// baseline (297.897 us; speedup 1.0000x reference)
//
#include <hip/hip_runtime.h>
#include <hip/hip_bf16.h>

// Problem constants
constexpr int   DIMC  = 512;
constexpr int   PARTC = 6;
constexpr int   NTOK  = 162;
constexpr float SCALING = 22.62741699796952f; // sqrt(512)
constexpr float LNEPS   = 1e-5f;

typedef __attribute__((ext_vector_type(8))) short bf16x8;
typedef __attribute__((ext_vector_type(4))) float f32x4;

// ---------------------------------------------------------------------------
// K0: transpose f32 [R][C] -> bf16 [C][R]
// ---------------------------------------------------------------------------
__global__ __launch_bounds__(256) void transpose_f32_bf16(
    const float* __restrict__ in, __hip_bfloat16* __restrict__ outp, int R, int C)
{
  __shared__ float tile[32][33];
  const int tx = threadIdx.x, ty = threadIdx.y;
  const int bx = blockIdx.x, by = blockIdx.y;
  const int c = bx * 32 + tx;
#pragma unroll
  for (int i = 0; i < 32; i += 8) {
    int r = by * 32 + ty + i;
    tile[ty + i][tx] = in[(size_t)r * C + c];
  }
  __syncthreads();
#pragma unroll
  for (int i = 0; i < 32; i += 8) {
    outp[(size_t)(bx * 32 + ty + i) * R + by * 32 + tx] =
        __float2bfloat16(tile[tx][ty + i]);
  }
}

// ---------------------------------------------------------------------------
// S1 (R14/R18 verbatim): SINGLE-PASS fused attention + /sqrt(512) + LN.
// ATTRIBUTION ROUND: launched TWICE (idempotent) — total delta vs R18
// directly measures one warm attn execution.
// ---------------------------------------------------------------------------
__global__ __launch_bounds__(256, 3) void attn_ln_k(
    const float* __restrict__ x,     // [1024][162][512]
    const float* __restrict__ pt,    // [6][512]
    const float* __restrict__ g,     // [512]
    const float* __restrict__ bta,   // [512]
    __hip_bfloat16* __restrict__ outp)
{
  const int b = blockIdx.x;
  const int tid = threadIdx.x;
  const int w = tid >> 6;
  const int lane = tid & 63;
  const float* __restrict__ xb = x + (size_t)b * (NTOK * DIMC);

  __shared__ __align__(16) float ulds[2][PARTC][DIMC];  // 24 KB
  __shared__ float s_lw[4][PARTC];
  __shared__ float s_red[4][2 * PARTC];

  // pt slice for this lane: dims [8l, 8l+8)
  float4 pA[PARTC], pB[PARTC];
#pragma unroll
  for (int p = 0; p < PARTC; ++p) {
    pA[p] = *(const float4*)(pt + p * DIMC + 8 * lane);
    pB[p] = *(const float4*)(pt + p * DIMC + 8 * lane + 4);
  }

  float u[PARTC][8];
  float l[PARTC];
#pragma unroll
  for (int p = 0; p < PARTC; ++p) {
    l[p] = 0.f;
#pragma unroll
    for (int j = 0; j < 8; ++j) u[p][j] = 0.f;
  }

  // ---- single pass: logits + online PV accumulate (no barriers) ----
  for (int n = w; n < NTOK; n += 4) {
    const float* xr = xb + (size_t)n * DIMC + 8 * lane;
    float4 xa = *(const float4*)xr;
    float4 xc = *(const float4*)(xr + 4);

    float acc[PARTC];
#pragma unroll
    for (int p = 0; p < PARTC; ++p) {
      acc[p] = xa.x * pA[p].x + xa.y * pA[p].y + xa.z * pA[p].z + xa.w * pA[p].w
             + xc.x * pB[p].x + xc.y * pB[p].y + xc.z * pB[p].z + xc.w * pB[p].w;
    }
#pragma unroll
    for (int off = 32; off > 0; off >>= 1) {
#pragma unroll
      for (int p = 0; p < PARTC; ++p) acc[p] += __shfl_xor(acc[p], off);
    }
#pragma unroll
    for (int p = 0; p < PARTC; ++p) {
      const float we = __expf(acc[p]);   // fixed-max softmax (M=0)
      l[p] += we;
      u[p][0] += we * xa.x; u[p][1] += we * xa.y;
      u[p][2] += we * xa.z; u[p][3] += we * xa.w;
      u[p][4] += we * xc.x; u[p][5] += we * xc.y;
      u[p][6] += we * xc.z; u[p][7] += we * xc.w;
    }
  }

  // ---- merge the 4 waves' partial (u, l) ----
  if (w >= 2) {
#pragma unroll
    for (int p = 0; p < PARTC; ++p) {
      *(float4*)&ulds[w - 2][p][8 * lane]     = make_float4(u[p][0], u[p][1], u[p][2], u[p][3]);
      *(float4*)&ulds[w - 2][p][8 * lane + 4] = make_float4(u[p][4], u[p][5], u[p][6], u[p][7]);
    }
    if (lane == 0) {
#pragma unroll
      for (int p = 0; p < PARTC; ++p) s_lw[w][p] = l[p];
    }
  }
  __syncthreads();
  if (w < 2) {
#pragma unroll
    for (int p = 0; p < PARTC; ++p) {
      float4 a = *(const float4*)&ulds[w][p][8 * lane];
      float4 c = *(const float4*)&ulds[w][p][8 * lane + 4];
      a.x += u[p][0]; a.y += u[p][1]; a.z += u[p][2]; a.w += u[p][3];
      c.x += u[p][4]; c.y += u[p][5]; c.z += u[p][6]; c.w += u[p][7];
      *(float4*)&ulds[w][p][8 * lane]     = a;
      *(float4*)&ulds[w][p][8 * lane + 4] = c;
    }
    if (lane == 0) {
#pragma unroll
      for (int p = 0; p < PARTC; ++p) s_lw[w][p] = l[p];
    }
  }
  __syncthreads();

  // ---- epilogue: thread owns dims (2t, 2t+1); y = u/(l*sqrt(512)); LN ----
  float lt[PARTC];
#pragma unroll
  for (int p = 0; p < PARTC; ++p)
    lt[p] = s_lw[0][p] + s_lw[1][p] + s_lw[2][p] + s_lw[3][p];

  float y0[PARTC], y1[PARTC], s1[PARTC], s2[PARTC];
#pragma unroll
  for (int p = 0; p < PARTC; ++p) {
    const float uu0 = ulds[0][p][2 * tid]     + ulds[1][p][2 * tid];
    const float uu1 = ulds[0][p][2 * tid + 1] + ulds[1][p][2 * tid + 1];
    const float inv = 1.f / (lt[p] * SCALING);
    y0[p] = uu0 * inv;
    y1[p] = uu1 * inv;
    s1[p] = y0[p] + y1[p];
    s2[p] = y0[p] * y0[p] + y1[p] * y1[p];
  }
#pragma unroll
  for (int off = 32; off > 0; off >>= 1) {
#pragma unroll
    for (int p = 0; p < PARTC; ++p) {
      s1[p] += __shfl_xor(s1[p], off);
      s2[p] += __shfl_xor(s2[p], off);
    }
  }
  if (lane == 0) {
#pragma unroll
    for (int p = 0; p < PARTC; ++p) {
      s_red[w][p] = s1[p];
      s_red[w][PARTC + p] = s2[p];
    }
  }
  __syncthreads();

  const float ga0 = g[2 * tid], ga1 = g[2 * tid + 1];
  const float bb0 = bta[2 * tid], bb1 = bta[2 * tid + 1];
  __hip_bfloat16* orow = outp + (size_t)b * PARTC * DIMC;
#pragma unroll
  for (int p = 0; p < PARTC; ++p) {
    float S = s_red[0][p] + s_red[1][p] + s_red[2][p] + s_red[3][p];
    float Q = s_red[0][PARTC + p] + s_red[1][PARTC + p] + s_red[2][PARTC + p] + s_red[3][PARTC + p];
    float mu = S * (1.f / 512.f);
    float var = Q * (1.f / 512.f) - mu * mu;
    float r = rsqrtf(var + LNEPS);
    __hip_bfloat162 hv;
    hv.x = __float2bfloat16((y0[p] - mu) * r * ga0 + bb0);
    hv.y = __float2bfloat16((y1[p] - mu) * r * ga1 + bb1);
    *(__hip_bfloat162*)(orow + p * DIMC + 2 * tid) = hv;
  }
}

// ---------------------------------------------------------------------------
// MFMA GEMM: C[M][N] = act(A[M][K] @ Bt[N][K]^T + bias)   (unchanged)
// ---------------------------------------------------------------------------
template <int BM, int BN, bool GELU>
__global__ __launch_bounds__(256) void gemm_bt(
    const __hip_bfloat16* __restrict__ A,
    const __hip_bfloat16* __restrict__ Bt,
    const float* __restrict__ bias,
    void* __restrict__ Cv,
    int M, int N, int K)
{
  constexpr int BK = 64;
  constexpr int LDT = BK + 16; // 80 bf16 = 160B row stride
  __shared__ __align__(16) unsigned short Al[BM][LDT];
  __shared__ __align__(16) unsigned short Bl[BN][LDT];

  const int tid = threadIdx.x;
  const int w = tid >> 6, lane = tid & 63;
  const int wr = w >> 1, wc = w & 1;
  const int tm = blockIdx.y * BM, tn = blockIdx.x * BN;
  constexpr int FM = BM / 32, FN = BN / 32;

  f32x4 acc[FM][FN];
#pragma unroll
  for (int m = 0; m < FM; ++m)
#pragma unroll
    for (int n = 0; n < FN; ++n) acc[m][n] = (f32x4){0.f, 0.f, 0.f, 0.f};

  const int srow = tid >> 3;        // 0..31
  const int scol = (tid & 7) * 8;   // element offset in K

  for (int k0 = 0; k0 < K; k0 += BK) {
    __syncthreads();
#pragma unroll
    for (int r = 0; r < BM / 32; ++r) {
      int row = r * 32 + srow;
      *(int4*)(&Al[row][scol]) =
          *(const int4*)(A + (size_t)(tm + row) * K + k0 + scol);
    }
#pragma unroll
    for (int r = 0; r < BN / 32; ++r) {
      int row = r * 32 + srow;
      *(int4*)(&Bl[row][scol]) =
          *(const int4*)(Bt + (size_t)(tn + row) * K + k0 + scol);
    }
    __syncthreads();

#pragma unroll
    for (int kk = 0; kk < 2; ++kk) {
      const int ko = kk * 32 + (lane >> 4) * 8;
      bf16x8 af[FM], bfr[FN];
#pragma unroll
      for (int m = 0; m < FM; ++m)
        af[m] = *(const bf16x8*)(&Al[wr * (BM / 2) + m * 16 + (lane & 15)][ko]);
#pragma unroll
      for (int n = 0; n < FN; ++n)
        bfr[n] = *(const bf16x8*)(&Bl[wc * (BN / 2) + n * 16 + (lane & 15)][ko]);
#pragma unroll
      for (int m = 0; m < FM; ++m)
#pragma unroll
        for (int n = 0; n < FN; ++n)
          acc[m][n] = __builtin_amdgcn_mfma_f32_16x16x32_bf16(
              af[m], bfr[n], acc[m][n], 0, 0, 0);
    }
  }

  // Epilogue: C/D layout col = lane&15, row = (lane>>4)*4 + r  [m89-verified]
  const int cl = lane & 15, rg = (lane >> 4) * 4;
#pragma unroll
  for (int m = 0; m < FM; ++m) {
#pragma unroll
    for (int n = 0; n < FN; ++n) {
      int col = tn + wc * (BN / 2) + n * 16 + cl;
      float bv = bias[col];
#pragma unroll
      for (int r = 0; r < 4; ++r) {
        int row = tm + wr * (BM / 2) + m * 16 + rg + r;
        float v = acc[m][n][r] + bv;
        if (GELU) {
          v = 0.5f * v * (1.f + erff(v * 0.7071067811865476f));
          ((__hip_bfloat16*)Cv)[(size_t)row * N + col] = __float2bfloat16(v);
        } else {
          ((float*)Cv)[(size_t)row * N + col] = v;
        }
      }
    }
  }
}

// ---------------------------------------------------------------------------
extern "C" void kernel_launch(void* const* d_in, const int* in_sizes, int n_in,
                              void* d_out, int out_size, void* d_ws, size_t ws_size,
                              hipStream_t stream)
{
  const float* x   = (const float*)d_in[0];
  const float* pt  = (const float*)d_in[1];
  const float* g   = (const float*)d_in[2];
  const float* bta = (const float*)d_in[3];
  const float* W1  = (const float*)d_in[4];
  const float* b1  = (const float*)d_in[5];
  const float* W2  = (const float*)d_in[6];
  const float* b2  = (const float*)d_in[7];
  float* outp = (float*)d_out;

  char* ws = (char*)d_ws;
  __hip_bfloat16* W1T = (__hip_bfloat16*)(ws);                    // 2048x512  bf16 (2 MB)
  __hip_bfloat16* W2T = (__hip_bfloat16*)(ws + 2097152);          // 512x2048  bf16 (2 MB)
  __hip_bfloat16* LNO = (__hip_bfloat16*)(ws + 4194304);          // 6144x512  bf16 (6 MB)
  __hip_bfloat16* H   = (__hip_bfloat16*)(ws + 10485760);         // 6144x2048 bf16 (25 MB)

  // K0: W1 (512x2048) -> W1T (2048x512); W2 (2048x512) -> W2T (512x2048)
  transpose_f32_bf16<<<dim3(2048 / 32, 512 / 32), dim3(32, 8), 0, stream>>>(W1, W1T, 512, 2048);
  transpose_f32_bf16<<<dim3(512 / 32, 2048 / 32), dim3(32, 8), 0, stream>>>(W2, W2T, 2048, 512);

  // S1: single-pass fused attention + LN -> LNO.
  // *** ATTRIBUTION: launched twice (idempotent). Total delta vs R18 (188.8)
  // *** directly measures one warm attn execution.
  attn_ln_k<<<1024, 256, 0, stream>>>(x, pt, g, bta, LNO);
  attn_ln_k<<<1024, 256, 0, stream>>>(x, pt, g, bta, LNO);

  // K2: h = gelu(LNO @ W1 + b1) -> H (bf16)
  gemm_bt<128, 128, true><<<dim3(2048 / 128, 6144 / 128), 256, 0, stream>>>(
      LNO, W1T, b1, (void*)H, 6144, 2048, 512);

  // K3: out = H @ W2 + b2 -> d_out (f32)  — BM=128: 16 MFMAs/K-step
  gemm_bt<128, 64, false><<<dim3(512 / 64, 6144 / 128), 256, 0, stream>>>(
      H, W2T, b2, (void*)outp, 6144, 512, 2048);
}

// Round 20
// 190.698 us; speedup vs baseline: 1.5621x; 1.5621x over previous
//
#include <hip/hip_runtime.h>
#include <hip/hip_bf16.h>

// Problem constants
constexpr int   DIMC  = 512;
constexpr int   PARTC = 6;
constexpr int   NTOK  = 162;
constexpr int   HALF  = 81;    // tokens per split-block (162/2)
constexpr float SCALING = 22.62741699796952f; // sqrt(512)
constexpr float LNEPS   = 1e-5f;

typedef __attribute__((ext_vector_type(8))) short bf16x8;
typedef __attribute__((ext_vector_type(4))) float f32x4;

// ---------------------------------------------------------------------------
// K0: transpose f32 [R][C] -> bf16 [C][R]
// ---------------------------------------------------------------------------
__global__ __launch_bounds__(256) void transpose_f32_bf16(
    const float* __restrict__ in, __hip_bfloat16* __restrict__ outp, int R, int C)
{
  __shared__ float tile[32][33];
  const int tx = threadIdx.x, ty = threadIdx.y;
  const int bx = blockIdx.x, by = blockIdx.y;
  const int c = bx * 32 + tx;
#pragma unroll
  for (int i = 0; i < 32; i += 8) {
    int r = by * 32 + ty + i;
    tile[ty + i][tx] = in[(size_t)r * C + c];
  }
  __syncthreads();
#pragma unroll
  for (int i = 0; i < 32; i += 8) {
    outp[(size_t)(bx * 32 + ty + i) * R + by * 32 + tx] =
        __float2bfloat16(tile[tx][ty + i]);
  }
}

// ---------------------------------------------------------------------------
// P1: split-b attention partials.  Block bh handles b = bh>>1, tokens
// [81*(bh&1), 81*(bh&1)+81).  S1 hot loop verbatim on half the tokens
// (halves per-wave serial chain; doubles resident waves/outstanding loads).
// Writes block-partial u[6][512] f32 + l[6] to workspace.
// ---------------------------------------------------------------------------
__global__ __launch_bounds__(256, 3) void attn_part_k(
    const float* __restrict__ x,     // [1024][162][512]
    const float* __restrict__ pt,    // [6][512]
    float* __restrict__ UP,          // [2048][6][512]
    float* __restrict__ LP)          // [2048][6]
{
  const int bh = blockIdx.x;         // 0..2047
  const int b = bh >> 1;
  const int base = (bh & 1) * HALF;
  const int tid = threadIdx.x;
  const int w = tid >> 6;
  const int lane = tid & 63;
  const float* __restrict__ xb = x + (size_t)b * (NTOK * DIMC);

  __shared__ __align__(16) float ulds[2][PARTC][DIMC];  // 24 KB
  __shared__ float s_lw[4][PARTC];

  float4 pA[PARTC], pB[PARTC];
#pragma unroll
  for (int p = 0; p < PARTC; ++p) {
    pA[p] = *(const float4*)(pt + p * DIMC + 8 * lane);
    pB[p] = *(const float4*)(pt + p * DIMC + 8 * lane + 4);
  }

  float u[PARTC][8];
  float l[PARTC];
#pragma unroll
  for (int p = 0; p < PARTC; ++p) {
    l[p] = 0.f;
#pragma unroll
    for (int j = 0; j < 8; ++j) u[p][j] = 0.f;
  }

  // ---- hot loop: logits + online PV accumulate (no barriers) ----
  for (int n = base + w; n < base + HALF; n += 4) {
    const float* xr = xb + (size_t)n * DIMC + 8 * lane;
    float4 xa = *(const float4*)xr;
    float4 xc = *(const float4*)(xr + 4);

    float acc[PARTC];
#pragma unroll
    for (int p = 0; p < PARTC; ++p) {
      acc[p] = xa.x * pA[p].x + xa.y * pA[p].y + xa.z * pA[p].z + xa.w * pA[p].w
             + xc.x * pB[p].x + xc.y * pB[p].y + xc.z * pB[p].z + xc.w * pB[p].w;
    }
#pragma unroll
    for (int off = 32; off > 0; off >>= 1) {
#pragma unroll
      for (int p = 0; p < PARTC; ++p) acc[p] += __shfl_xor(acc[p], off);
    }
#pragma unroll
    for (int p = 0; p < PARTC; ++p) {
      const float we = __expf(acc[p]);   // fixed-max softmax (M=0)
      l[p] += we;
      u[p][0] += we * xa.x; u[p][1] += we * xa.y;
      u[p][2] += we * xa.z; u[p][3] += we * xa.w;
      u[p][4] += we * xc.x; u[p][5] += we * xc.y;
      u[p][6] += we * xc.z; u[p][7] += we * xc.w;
    }
  }

  // ---- merge the 4 waves' partial (u, l) ----
  if (w >= 2) {
#pragma unroll
    for (int p = 0; p < PARTC; ++p) {
      *(float4*)&ulds[w - 2][p][8 * lane]     = make_float4(u[p][0], u[p][1], u[p][2], u[p][3]);
      *(float4*)&ulds[w - 2][p][8 * lane + 4] = make_float4(u[p][4], u[p][5], u[p][6], u[p][7]);
    }
    if (lane == 0) {
#pragma unroll
      for (int p = 0; p < PARTC; ++p) s_lw[w][p] = l[p];
    }
  }
  __syncthreads();
  if (w < 2) {
#pragma unroll
    for (int p = 0; p < PARTC; ++p) {
      float4 a = *(const float4*)&ulds[w][p][8 * lane];
      float4 c = *(const float4*)&ulds[w][p][8 * lane + 4];
      a.x += u[p][0]; a.y += u[p][1]; a.z += u[p][2]; a.w += u[p][3];
      c.x += u[p][4]; c.y += u[p][5]; c.z += u[p][6]; c.w += u[p][7];
      *(float4*)&ulds[w][p][8 * lane]     = a;
      *(float4*)&ulds[w][p][8 * lane + 4] = c;
    }
    if (lane == 0) {
#pragma unroll
      for (int p = 0; p < PARTC; ++p) s_lw[w][p] = l[p];
    }
  }
  __syncthreads();

  // ---- write block partials: thread owns dims (2t, 2t+1) ----
  float* __restrict__ up = UP + (size_t)bh * PARTC * DIMC;
#pragma unroll
  for (int p = 0; p < PARTC; ++p) {
    float2 v;
    v.x = ulds[0][p][2 * tid]     + ulds[1][p][2 * tid];
    v.y = ulds[0][p][2 * tid + 1] + ulds[1][p][2 * tid + 1];
    *(float2*)&up[p * DIMC + 2 * tid] = v;
  }
  if (tid < PARTC)
    LP[(size_t)bh * PARTC + tid] =
        s_lw[0][tid] + s_lw[1][tid] + s_lw[2][tid] + s_lw[3][tid];
}

// ---------------------------------------------------------------------------
// P2: merge two partials + /sqrt(512) + LayerNorm.  Block = one b, 256 thr.
// ---------------------------------------------------------------------------
__global__ __launch_bounds__(256, 4) void attn_merge_ln_k(
    const float* __restrict__ UP,    // [2048][6][512]
    const float* __restrict__ LP,    // [2048][6]
    const float* __restrict__ g,
    const float* __restrict__ bta,
    __hip_bfloat16* __restrict__ outp)
{
  const int b = blockIdx.x;
  const int tid = threadIdx.x;
  const int w = tid >> 6;
  const int lane = tid & 63;

  __shared__ float s_red[4][2 * PARTC];

  const float* __restrict__ up0 = UP + (size_t)(2 * b) * PARTC * DIMC;
  const float* __restrict__ up1 = up0 + PARTC * DIMC;

  float lt[PARTC];
#pragma unroll
  for (int p = 0; p < PARTC; ++p)
    lt[p] = LP[(size_t)(2 * b) * PARTC + p] + LP[(size_t)(2 * b + 1) * PARTC + p];

  float y0[PARTC], y1[PARTC], s1[PARTC], s2[PARTC];
#pragma unroll
  for (int p = 0; p < PARTC; ++p) {
    float2 a = *(const float2*)&up0[p * DIMC + 2 * tid];
    float2 c = *(const float2*)&up1[p * DIMC + 2 * tid];
    const float inv = 1.f / (lt[p] * SCALING);
    y0[p] = (a.x + c.x) * inv;
    y1[p] = (a.y + c.y) * inv;
    s1[p] = y0[p] + y1[p];
    s2[p] = y0[p] * y0[p] + y1[p] * y1[p];
  }
#pragma unroll
  for (int off = 32; off > 0; off >>= 1) {
#pragma unroll
    for (int p = 0; p < PARTC; ++p) {
      s1[p] += __shfl_xor(s1[p], off);
      s2[p] += __shfl_xor(s2[p], off);
    }
  }
  if (lane == 0) {
#pragma unroll
    for (int p = 0; p < PARTC; ++p) {
      s_red[w][p] = s1[p];
      s_red[w][PARTC + p] = s2[p];
    }
  }
  __syncthreads();

  const float ga0 = g[2 * tid], ga1 = g[2 * tid + 1];
  const float bb0 = bta[2 * tid], bb1 = bta[2 * tid + 1];
  __hip_bfloat16* orow = outp + (size_t)b * PARTC * DIMC;
#pragma unroll
  for (int p = 0; p < PARTC; ++p) {
    float S = s_red[0][p] + s_red[1][p] + s_red[2][p] + s_red[3][p];
    float Q = s_red[0][PARTC + p] + s_red[1][PARTC + p] + s_red[2][PARTC + p] + s_red[3][PARTC + p];
    float mu = S * (1.f / 512.f);
    float var = Q * (1.f / 512.f) - mu * mu;
    float r = rsqrtf(var + LNEPS);
    __hip_bfloat162 hv;
    hv.x = __float2bfloat16((y0[p] - mu) * r * ga0 + bb0);
    hv.y = __float2bfloat16((y1[p] - mu) * r * ga1 + bb1);
    *(__hip_bfloat162*)(orow + p * DIMC + 2 * tid) = hv;
  }
}

// ---------------------------------------------------------------------------
// MFMA GEMM: C[M][N] = act(A[M][K] @ Bt[N][K]^T + bias)   (unchanged)
// ---------------------------------------------------------------------------
template <int BM, int BN, bool GELU>
__global__ __launch_bounds__(256) void gemm_bt(
    const __hip_bfloat16* __restrict__ A,
    const __hip_bfloat16* __restrict__ Bt,
    const float* __restrict__ bias,
    void* __restrict__ Cv,
    int M, int N, int K)
{
  constexpr int BK = 64;
  constexpr int LDT = BK + 16; // 80 bf16 = 160B row stride
  __shared__ __align__(16) unsigned short Al[BM][LDT];
  __shared__ __align__(16) unsigned short Bl[BN][LDT];

  const int tid = threadIdx.x;
  const int w = tid >> 6, lane = tid & 63;
  const int wr = w >> 1, wc = w & 1;
  const int tm = blockIdx.y * BM, tn = blockIdx.x * BN;
  constexpr int FM = BM / 32, FN = BN / 32;

  f32x4 acc[FM][FN];
#pragma unroll
  for (int m = 0; m < FM; ++m)
#pragma unroll
    for (int n = 0; n < FN; ++n) acc[m][n] = (f32x4){0.f, 0.f, 0.f, 0.f};

  const int srow = tid >> 3;        // 0..31
  const int scol = (tid & 7) * 8;   // element offset in K

  for (int k0 = 0; k0 < K; k0 += BK) {
    __syncthreads();
#pragma unroll
    for (int r = 0; r < BM / 32; ++r) {
      int row = r * 32 + srow;
      *(int4*)(&Al[row][scol]) =
          *(const int4*)(A + (size_t)(tm + row) * K + k0 + scol);
    }
#pragma unroll
    for (int r = 0; r < BN / 32; ++r) {
      int row = r * 32 + srow;
      *(int4*)(&Bl[row][scol]) =
          *(const int4*)(Bt + (size_t)(tn + row) * K + k0 + scol);
    }
    __syncthreads();

#pragma unroll
    for (int kk = 0; kk < 2; ++kk) {
      const int ko = kk * 32 + (lane >> 4) * 8;
      bf16x8 af[FM], bfr[FN];
#pragma unroll
      for (int m = 0; m < FM; ++m)
        af[m] = *(const bf16x8*)(&Al[wr * (BM / 2) + m * 16 + (lane & 15)][ko]);
#pragma unroll
      for (int n = 0; n < FN; ++n)
        bfr[n] = *(const bf16x8*)(&Bl[wc * (BN / 2) + n * 16 + (lane & 15)][ko]);
#pragma unroll
      for (int m = 0; m < FM; ++m)
#pragma unroll
        for (int n = 0; n < FN; ++n)
          acc[m][n] = __builtin_amdgcn_mfma_f32_16x16x32_bf16(
              af[m], bfr[n], acc[m][n], 0, 0, 0);
    }
  }

  // Epilogue: C/D layout col = lane&15, row = (lane>>4)*4 + r  [m89-verified]
  const int cl = lane & 15, rg = (lane >> 4) * 4;
#pragma unroll
  for (int m = 0; m < FM; ++m) {
#pragma unroll
    for (int n = 0; n < FN; ++n) {
      int col = tn + wc * (BN / 2) + n * 16 + cl;
      float bv = bias[col];
#pragma unroll
      for (int r = 0; r < 4; ++r) {
        int row = tm + wr * (BM / 2) + m * 16 + rg + r;
        float v = acc[m][n][r] + bv;
        if (GELU) {
          v = 0.5f * v * (1.f + erff(v * 0.7071067811865476f));
          ((__hip_bfloat16*)Cv)[(size_t)row * N + col] = __float2bfloat16(v);
        } else {
          ((float*)Cv)[(size_t)row * N + col] = v;
        }
      }
    }
  }
}

// ---------------------------------------------------------------------------
extern "C" void kernel_launch(void* const* d_in, const int* in_sizes, int n_in,
                              void* d_out, int out_size, void* d_ws, size_t ws_size,
                              hipStream_t stream)
{
  const float* x   = (const float*)d_in[0];
  const float* pt  = (const float*)d_in[1];
  const float* g   = (const float*)d_in[2];
  const float* bta = (const float*)d_in[3];
  const float* W1  = (const float*)d_in[4];
  const float* b1  = (const float*)d_in[5];
  const float* W2  = (const float*)d_in[6];
  const float* b2  = (const float*)d_in[7];
  float* outp = (float*)d_out;

  char* ws = (char*)d_ws;
  __hip_bfloat16* W1T = (__hip_bfloat16*)(ws);                    // 2048x512  bf16 (2 MB)
  __hip_bfloat16* W2T = (__hip_bfloat16*)(ws + 2097152);          // 512x2048  bf16 (2 MB)
  __hip_bfloat16* LNO = (__hip_bfloat16*)(ws + 4194304);          // 6144x512  bf16 (6 MB)
  __hip_bfloat16* H   = (__hip_bfloat16*)(ws + 10485760);         // 6144x2048 bf16 (25 MB)
  float*          UP  = (float*)(ws + 35651584);                  // 2048x6x512 f32 (25 MB)
  float*          LP  = (float*)(ws + 60817408);                  // 2048x6 f32 (48 KB)

  // K0: W1 (512x2048) -> W1T (2048x512); W2 (2048x512) -> W2T (512x2048)
  transpose_f32_bf16<<<dim3(2048 / 32, 512 / 32), dim3(32, 8), 0, stream>>>(W1, W1T, 512, 2048);
  transpose_f32_bf16<<<dim3(512 / 32, 2048 / 32), dim3(32, 8), 0, stream>>>(W2, W2T, 2048, 512);

  // P1: split-b attention partials (2048 blocks, ~20 tokens/wave)
  attn_part_k<<<2048, 256, 0, stream>>>(x, pt, UP, LP);

  // P2: merge + LN -> LNO
  attn_merge_ln_k<<<1024, 256, 0, stream>>>(UP, LP, g, bta, LNO);

  // K2: h = gelu(LNO @ W1 + b1) -> H (bf16)
  gemm_bt<128, 128, true><<<dim3(2048 / 128, 6144 / 128), 256, 0, stream>>>(
      LNO, W1T, b1, (void*)H, 6144, 2048, 512);

  // K3: out = H @ W2 + b2 -> d_out (f32)  — BM=128: 16 MFMAs/K-step
  gemm_bt<128, 64, false><<<dim3(512 / 64, 6144 / 128), 256, 0, stream>>>(
      H, W2T, b2, (void*)outp, 6144, 512, 2048);
}

// Round 21
// 189.210 us; speedup vs baseline: 1.5744x; 1.0079x over previous
//
#include <hip/hip_runtime.h>
#include <hip/hip_bf16.h>

// Problem constants
constexpr int   DIMC  = 512;
constexpr int   PARTC = 6;
constexpr int   NTOK  = 162;
constexpr float SCALING = 22.62741699796952f; // sqrt(512)
constexpr float LNEPS   = 1e-5f;

typedef __attribute__((ext_vector_type(8))) short bf16x8;
typedef __attribute__((ext_vector_type(4))) float f32x4;

// ---------------------------------------------------------------------------
// K0: transpose f32 [R][C] -> bf16 [C][R]
// ---------------------------------------------------------------------------
__global__ __launch_bounds__(256) void transpose_f32_bf16(
    const float* __restrict__ in, __hip_bfloat16* __restrict__ outp, int R, int C)
{
  __shared__ float tile[32][33];
  const int tx = threadIdx.x, ty = threadIdx.y;
  const int bx = blockIdx.x, by = blockIdx.y;
  const int c = bx * 32 + tx;
#pragma unroll
  for (int i = 0; i < 32; i += 8) {
    int r = by * 32 + ty + i;
    tile[ty + i][tx] = in[(size_t)r * C + c];
  }
  __syncthreads();
#pragma unroll
  for (int i = 0; i < 32; i += 8) {
    outp[(size_t)(bx * 32 + ty + i) * R + by * 32 + tx] =
        __float2bfloat16(tile[tx][ty + i]);
  }
}

// ---------------------------------------------------------------------------
// S3: S1 (R18) + LOAD-ONLY software pipeline: token n+4's row is loaded into
// 8 spare VGPRs BEFORE token n's dot/shfl/exp chain, so next-token loads are
// in flight across the whole ~400cy chain (doubles per-wave outstanding
// bytes; +8 VGPR only — R17's full-chain unroll spilled, this can't).
// Everything else identical to R18's proven S1.
// ---------------------------------------------------------------------------
__global__ __launch_bounds__(256, 3) void attn_ln_k(
    const float* __restrict__ x,     // [1024][162][512]
    const float* __restrict__ pt,    // [6][512]
    const float* __restrict__ g,     // [512]
    const float* __restrict__ bta,   // [512]
    __hip_bfloat16* __restrict__ outp)
{
  const int b = blockIdx.x;
  const int tid = threadIdx.x;
  const int w = tid >> 6;
  const int lane = tid & 63;
  const float* __restrict__ xb = x + (size_t)b * (NTOK * DIMC);

  __shared__ __align__(16) float ulds[2][PARTC][DIMC];  // 24 KB
  __shared__ float s_lw[4][PARTC];
  __shared__ float s_red[4][2 * PARTC];

  // pt slice for this lane: dims [8l, 8l+8)
  float4 pA[PARTC], pB[PARTC];
#pragma unroll
  for (int p = 0; p < PARTC; ++p) {
    pA[p] = *(const float4*)(pt + p * DIMC + 8 * lane);
    pB[p] = *(const float4*)(pt + p * DIMC + 8 * lane + 4);
  }

  float u[PARTC][8];
  float l[PARTC];
#pragma unroll
  for (int p = 0; p < PARTC; ++p) {
    l[p] = 0.f;
#pragma unroll
    for (int j = 0; j < 8; ++j) u[p][j] = 0.f;
  }

  // ---- single pass with next-token load prefetch (no barriers) ----
  const float* xr0 = xb + (size_t)w * DIMC + 8 * lane;
  float4 xa = *(const float4*)xr0;
  float4 xc = *(const float4*)(xr0 + 4);

  for (int n = w; n < NTOK; n += 4) {
    // issue next token's loads FIRST (clamped; in flight across the chain)
    const int nn = min(n + 4, NTOK - 1);
    const float* xrn = xb + (size_t)nn * DIMC + 8 * lane;
    float4 na = *(const float4*)xrn;
    float4 nc = *(const float4*)(xrn + 4);

    float acc[PARTC];
#pragma unroll
    for (int p = 0; p < PARTC; ++p) {
      acc[p] = xa.x * pA[p].x + xa.y * pA[p].y + xa.z * pA[p].z + xa.w * pA[p].w
             + xc.x * pB[p].x + xc.y * pB[p].y + xc.z * pB[p].z + xc.w * pB[p].w;
    }
#pragma unroll
    for (int off = 32; off > 0; off >>= 1) {
#pragma unroll
      for (int p = 0; p < PARTC; ++p) acc[p] += __shfl_xor(acc[p], off);
    }
#pragma unroll
    for (int p = 0; p < PARTC; ++p) {
      const float we = __expf(acc[p]);   // fixed-max softmax (M=0)
      l[p] += we;
      u[p][0] += we * xa.x; u[p][1] += we * xa.y;
      u[p][2] += we * xa.z; u[p][3] += we * xa.w;
      u[p][4] += we * xc.x; u[p][5] += we * xc.y;
      u[p][6] += we * xc.z; u[p][7] += we * xc.w;
    }
    xa = na; xc = nc;
  }

  // ---- merge the 4 waves' partial (u, l) ----
  if (w >= 2) {
#pragma unroll
    for (int p = 0; p < PARTC; ++p) {
      *(float4*)&ulds[w - 2][p][8 * lane]     = make_float4(u[p][0], u[p][1], u[p][2], u[p][3]);
      *(float4*)&ulds[w - 2][p][8 * lane + 4] = make_float4(u[p][4], u[p][5], u[p][6], u[p][7]);
    }
    if (lane == 0) {
#pragma unroll
      for (int p = 0; p < PARTC; ++p) s_lw[w][p] = l[p];
    }
  }
  __syncthreads();
  if (w < 2) {
#pragma unroll
    for (int p = 0; p < PARTC; ++p) {
      float4 a = *(const float4*)&ulds[w][p][8 * lane];
      float4 c = *(const float4*)&ulds[w][p][8 * lane + 4];
      a.x += u[p][0]; a.y += u[p][1]; a.z += u[p][2]; a.w += u[p][3];
      c.x += u[p][4]; c.y += u[p][5]; c.z += u[p][6]; c.w += u[p][7];
      *(float4*)&ulds[w][p][8 * lane]     = a;
      *(float4*)&ulds[w][p][8 * lane + 4] = c;
    }
    if (lane == 0) {
#pragma unroll
      for (int p = 0; p < PARTC; ++p) s_lw[w][p] = l[p];
    }
  }
  __syncthreads();

  // ---- epilogue: thread owns dims (2t, 2t+1); y = u/(l*sqrt(512)); LN ----
  float lt[PARTC];
#pragma unroll
  for (int p = 0; p < PARTC; ++p)
    lt[p] = s_lw[0][p] + s_lw[1][p] + s_lw[2][p] + s_lw[3][p];

  float y0[PARTC], y1[PARTC], s1[PARTC], s2[PARTC];
#pragma unroll
  for (int p = 0; p < PARTC; ++p) {
    const float uu0 = ulds[0][p][2 * tid]     + ulds[1][p][2 * tid];
    const float uu1 = ulds[0][p][2 * tid + 1] + ulds[1][p][2 * tid + 1];
    const float inv = 1.f / (lt[p] * SCALING);
    y0[p] = uu0 * inv;
    y1[p] = uu1 * inv;
    s1[p] = y0[p] + y1[p];
    s2[p] = y0[p] * y0[p] + y1[p] * y1[p];
  }
#pragma unroll
  for (int off = 32; off > 0; off >>= 1) {
#pragma unroll
    for (int p = 0; p < PARTC; ++p) {
      s1[p] += __shfl_xor(s1[p], off);
      s2[p] += __shfl_xor(s2[p], off);
    }
  }
  if (lane == 0) {
#pragma unroll
    for (int p = 0; p < PARTC; ++p) {
      s_red[w][p] = s1[p];
      s_red[w][PARTC + p] = s2[p];
    }
  }
  __syncthreads();

  const float ga0 = g[2 * tid], ga1 = g[2 * tid + 1];
  const float bb0 = bta[2 * tid], bb1 = bta[2 * tid + 1];
  __hip_bfloat16* orow = outp + (size_t)b * PARTC * DIMC;
#pragma unroll
  for (int p = 0; p < PARTC; ++p) {
    float S = s_red[0][p] + s_red[1][p] + s_red[2][p] + s_red[3][p];
    float Q = s_red[0][PARTC + p] + s_red[1][PARTC + p] + s_red[2][PARTC + p] + s_red[3][PARTC + p];
    float mu = S * (1.f / 512.f);
    float var = Q * (1.f / 512.f) - mu * mu;
    float r = rsqrtf(var + LNEPS);
    __hip_bfloat162 hv;
    hv.x = __float2bfloat16((y0[p] - mu) * r * ga0 + bb0);
    hv.y = __float2bfloat16((y1[p] - mu) * r * ga1 + bb1);
    *(__hip_bfloat162*)(orow + p * DIMC + 2 * tid) = hv;
  }
}

// ---------------------------------------------------------------------------
// MFMA GEMM: C[M][N] = act(A[M][K] @ Bt[N][K]^T + bias)   (unchanged)
// ---------------------------------------------------------------------------
template <int BM, int BN, bool GELU>
__global__ __launch_bounds__(256) void gemm_bt(
    const __hip_bfloat16* __restrict__ A,
    const __hip_bfloat16* __restrict__ Bt,
    const float* __restrict__ bias,
    void* __restrict__ Cv,
    int M, int N, int K)
{
  constexpr int BK = 64;
  constexpr int LDT = BK + 16; // 80 bf16 = 160B row stride
  __shared__ __align__(16) unsigned short Al[BM][LDT];
  __shared__ __align__(16) unsigned short Bl[BN][LDT];

  const int tid = threadIdx.x;
  const int w = tid >> 6, lane = tid & 63;
  const int wr = w >> 1, wc = w & 1;
  const int tm = blockIdx.y * BM, tn = blockIdx.x * BN;
  constexpr int FM = BM / 32, FN = BN / 32;

  f32x4 acc[FM][FN];
#pragma unroll
  for (int m = 0; m < FM; ++m)
#pragma unroll
    for (int n = 0; n < FN; ++n) acc[m][n] = (f32x4){0.f, 0.f, 0.f, 0.f};

  const int srow = tid >> 3;        // 0..31
  const int scol = (tid & 7) * 8;   // element offset in K

  for (int k0 = 0; k0 < K; k0 += BK) {
    __syncthreads();
#pragma unroll
    for (int r = 0; r < BM / 32; ++r) {
      int row = r * 32 + srow;
      *(int4*)(&Al[row][scol]) =
          *(const int4*)(A + (size_t)(tm + row) * K + k0 + scol);
    }
#pragma unroll
    for (int r = 0; r < BN / 32; ++r) {
      int row = r * 32 + srow;
      *(int4*)(&Bl[row][scol]) =
          *(const int4*)(Bt + (size_t)(tn + row) * K + k0 + scol);
    }
    __syncthreads();

#pragma unroll
    for (int kk = 0; kk < 2; ++kk) {
      const int ko = kk * 32 + (lane >> 4) * 8;
      bf16x8 af[FM], bfr[FN];
#pragma unroll
      for (int m = 0; m < FM; ++m)
        af[m] = *(const bf16x8*)(&Al[wr * (BM / 2) + m * 16 + (lane & 15)][ko]);
#pragma unroll
      for (int n = 0; n < FN; ++n)
        bfr[n] = *(const bf16x8*)(&Bl[wc * (BN / 2) + n * 16 + (lane & 15)][ko]);
#pragma unroll
      for (int m = 0; m < FM; ++m)
#pragma unroll
        for (int n = 0; n < FN; ++n)
          acc[m][n] = __builtin_amdgcn_mfma_f32_16x16x32_bf16(
              af[m], bfr[n], acc[m][n], 0, 0, 0);
    }
  }

  // Epilogue: C/D layout col = lane&15, row = (lane>>4)*4 + r  [m89-verified]
  const int cl = lane & 15, rg = (lane >> 4) * 4;
#pragma unroll
  for (int m = 0; m < FM; ++m) {
#pragma unroll
    for (int n = 0; n < FN; ++n) {
      int col = tn + wc * (BN / 2) + n * 16 + cl;
      float bv = bias[col];
#pragma unroll
      for (int r = 0; r < 4; ++r) {
        int row = tm + wr * (BM / 2) + m * 16 + rg + r;
        float v = acc[m][n][r] + bv;
        if (GELU) {
          v = 0.5f * v * (1.f + erff(v * 0.7071067811865476f));
          ((__hip_bfloat16*)Cv)[(size_t)row * N + col] = __float2bfloat16(v);
        } else {
          ((float*)Cv)[(size_t)row * N + col] = v;
        }
      }
    }
  }
}

// ---------------------------------------------------------------------------
extern "C" void kernel_launch(void* const* d_in, const int* in_sizes, int n_in,
                              void* d_out, int out_size, void* d_ws, size_t ws_size,
                              hipStream_t stream)
{
  const float* x   = (const float*)d_in[0];
  const float* pt  = (const float*)d_in[1];
  const float* g   = (const float*)d_in[2];
  const float* bta = (const float*)d_in[3];
  const float* W1  = (const float*)d_in[4];
  const float* b1  = (const float*)d_in[5];
  const float* W2  = (const float*)d_in[6];
  const float* b2  = (const float*)d_in[7];
  float* outp = (float*)d_out;

  char* ws = (char*)d_ws;
  __hip_bfloat16* W1T = (__hip_bfloat16*)(ws);                    // 2048x512  bf16 (2 MB)
  __hip_bfloat16* W2T = (__hip_bfloat16*)(ws + 2097152);          // 512x2048  bf16 (2 MB)
  __hip_bfloat16* LNO = (__hip_bfloat16*)(ws + 4194304);          // 6144x512  bf16 (6 MB)
  __hip_bfloat16* H   = (__hip_bfloat16*)(ws + 10485760);         // 6144x2048 bf16 (25 MB)

  // K0: W1 (512x2048) -> W1T (2048x512); W2 (2048x512) -> W2T (512x2048)
  transpose_f32_bf16<<<dim3(2048 / 32, 512 / 32), dim3(32, 8), 0, stream>>>(W1, W1T, 512, 2048);
  transpose_f32_bf16<<<dim3(512 / 32, 2048 / 32), dim3(32, 8), 0, stream>>>(W2, W2T, 2048, 512);

  // S3: single-pass fused attention + LN (load-prefetch pipeline) -> LNO
  attn_ln_k<<<1024, 256, 0, stream>>>(x, pt, g, bta, LNO);

  // K2: h = gelu(LNO @ W1 + b1) -> H (bf16)
  gemm_bt<128, 128, true><<<dim3(2048 / 128, 6144 / 128), 256, 0, stream>>>(
      LNO, W1T, b1, (void*)H, 6144, 2048, 512);

  // K3: out = H @ W2 + b2 -> d_out (f32)  — BM=128: 16 MFMAs/K-step
  gemm_bt<128, 64, false><<<dim3(512 / 64, 6144 / 128), 256, 0, stream>>>(
      H, W2T, b2, (void*)outp, 6144, 512, 2048);
}

// Round 23
// 185.851 us; speedup vs baseline: 1.6029x; 1.0181x over previous
//
#include <hip/hip_runtime.h>
#include <hip/hip_bf16.h>

// Problem constants
constexpr int   DIMC  = 512;
constexpr int   PARTC = 6;
constexpr int   NTOK  = 162;
constexpr float SCALING = 22.62741699796952f; // sqrt(512)
constexpr float LNEPS   = 1e-5f;

typedef __attribute__((ext_vector_type(8))) short bf16x8;
typedef __attribute__((ext_vector_type(4))) float f32x4;

// ---------------------------------------------------------------------------
// K0: transpose f32 [R][C] -> bf16 [C][R]
// ---------------------------------------------------------------------------
__global__ __launch_bounds__(256) void transpose_f32_bf16(
    const float* __restrict__ in, __hip_bfloat16* __restrict__ outp, int R, int C)
{
  __shared__ float tile[32][33];
  const int tx = threadIdx.x, ty = threadIdx.y;
  const int bx = blockIdx.x, by = blockIdx.y;
  const int c = bx * 32 + tx;
#pragma unroll
  for (int i = 0; i < 32; i += 8) {
    int r = by * 32 + ty + i;
    tile[ty + i][tx] = in[(size_t)r * C + c];
  }
  __syncthreads();
#pragma unroll
  for (int i = 0; i < 32; i += 8) {
    outp[(size_t)(bx * 32 + ty + i) * R + by * 32 + tx] =
        __float2bfloat16(tile[tx][ty + i]);
  }
}

// ---------------------------------------------------------------------------
// S4: R18's S1 with ONE change — x loads are NON-TEMPORAL (nt flag), now via
// native clang vector type f32x4 (the builtin rejects HIP_vector_type).
// Mechanism: x (340MB) thrashes the 256MB L3 at ~50% hit rate; blended
// L3/HBM path serves ~3.1 TB/s (R19 direct measurement: 109 µs warm).
// nt marks x lines evict-first -> stream served predominantly by HBM.
// ---------------------------------------------------------------------------
__global__ __launch_bounds__(256, 3) void attn_ln_k(
    const float* __restrict__ x,     // [1024][162][512]
    const float* __restrict__ pt,    // [6][512]
    const float* __restrict__ g,     // [512]
    const float* __restrict__ bta,   // [512]
    __hip_bfloat16* __restrict__ outp)
{
  const int b = blockIdx.x;
  const int tid = threadIdx.x;
  const int w = tid >> 6;
  const int lane = tid & 63;
  const float* __restrict__ xb = x + (size_t)b * (NTOK * DIMC);

  __shared__ __align__(16) float ulds[2][PARTC][DIMC];  // 24 KB
  __shared__ float s_lw[4][PARTC];
  __shared__ float s_red[4][2 * PARTC];

  // pt slice for this lane: dims [8l, 8l+8)
  float4 pA[PARTC], pB[PARTC];
#pragma unroll
  for (int p = 0; p < PARTC; ++p) {
    pA[p] = *(const float4*)(pt + p * DIMC + 8 * lane);
    pB[p] = *(const float4*)(pt + p * DIMC + 8 * lane + 4);
  }

  float u[PARTC][8];
  float l[PARTC];
#pragma unroll
  for (int p = 0; p < PARTC; ++p) {
    l[p] = 0.f;
#pragma unroll
    for (int j = 0; j < 8; ++j) u[p][j] = 0.f;
  }

  // ---- single pass: logits + online PV accumulate (no barriers) ----
  for (int n = w; n < NTOK; n += 4) {
    const float* xr = xb + (size_t)n * DIMC + 8 * lane;
    f32x4 xa = __builtin_nontemporal_load((const f32x4*)xr);
    f32x4 xc = __builtin_nontemporal_load((const f32x4*)(xr + 4));

    float acc[PARTC];
#pragma unroll
    for (int p = 0; p < PARTC; ++p) {
      acc[p] = xa[0] * pA[p].x + xa[1] * pA[p].y + xa[2] * pA[p].z + xa[3] * pA[p].w
             + xc[0] * pB[p].x + xc[1] * pB[p].y + xc[2] * pB[p].z + xc[3] * pB[p].w;
    }
#pragma unroll
    for (int off = 32; off > 0; off >>= 1) {
#pragma unroll
      for (int p = 0; p < PARTC; ++p) acc[p] += __shfl_xor(acc[p], off);
    }
#pragma unroll
    for (int p = 0; p < PARTC; ++p) {
      const float we = __expf(acc[p]);   // fixed-max softmax (M=0)
      l[p] += we;
      u[p][0] += we * xa[0]; u[p][1] += we * xa[1];
      u[p][2] += we * xa[2]; u[p][3] += we * xa[3];
      u[p][4] += we * xc[0]; u[p][5] += we * xc[1];
      u[p][6] += we * xc[2]; u[p][7] += we * xc[3];
    }
  }

  // ---- merge the 4 waves' partial (u, l) ----
  if (w >= 2) {
#pragma unroll
    for (int p = 0; p < PARTC; ++p) {
      *(float4*)&ulds[w - 2][p][8 * lane]     = make_float4(u[p][0], u[p][1], u[p][2], u[p][3]);
      *(float4*)&ulds[w - 2][p][8 * lane + 4] = make_float4(u[p][4], u[p][5], u[p][6], u[p][7]);
    }
    if (lane == 0) {
#pragma unroll
      for (int p = 0; p < PARTC; ++p) s_lw[w][p] = l[p];
    }
  }
  __syncthreads();
  if (w < 2) {
#pragma unroll
    for (int p = 0; p < PARTC; ++p) {
      float4 a = *(const float4*)&ulds[w][p][8 * lane];
      float4 c = *(const float4*)&ulds[w][p][8 * lane + 4];
      a.x += u[p][0]; a.y += u[p][1]; a.z += u[p][2]; a.w += u[p][3];
      c.x += u[p][4]; c.y += u[p][5]; c.z += u[p][6]; c.w += u[p][7];
      *(float4*)&ulds[w][p][8 * lane]     = a;
      *(float4*)&ulds[w][p][8 * lane + 4] = c;
    }
    if (lane == 0) {
#pragma unroll
      for (int p = 0; p < PARTC; ++p) s_lw[w][p] = l[p];
    }
  }
  __syncthreads();

  // ---- epilogue: thread owns dims (2t, 2t+1); y = u/(l*sqrt(512)); LN ----
  float lt[PARTC];
#pragma unroll
  for (int p = 0; p < PARTC; ++p)
    lt[p] = s_lw[0][p] + s_lw[1][p] + s_lw[2][p] + s_lw[3][p];

  float y0[PARTC], y1[PARTC], s1[PARTC], s2[PARTC];
#pragma unroll
  for (int p = 0; p < PARTC; ++p) {
    const float uu0 = ulds[0][p][2 * tid]     + ulds[1][p][2 * tid];
    const float uu1 = ulds[0][p][2 * tid + 1] + ulds[1][p][2 * tid + 1];
    const float inv = 1.f / (lt[p] * SCALING);
    y0[p] = uu0 * inv;
    y1[p] = uu1 * inv;
    s1[p] = y0[p] + y1[p];
    s2[p] = y0[p] * y0[p] + y1[p] * y1[p];
  }
#pragma unroll
  for (int off = 32; off > 0; off >>= 1) {
#pragma unroll
    for (int p = 0; p < PARTC; ++p) {
      s1[p] += __shfl_xor(s1[p], off);
      s2[p] += __shfl_xor(s2[p], off);
    }
  }
  if (lane == 0) {
#pragma unroll
    for (int p = 0; p < PARTC; ++p) {
      s_red[w][p] = s1[p];
      s_red[w][PARTC + p] = s2[p];
    }
  }
  __syncthreads();

  const float ga0 = g[2 * tid], ga1 = g[2 * tid + 1];
  const float bb0 = bta[2 * tid], bb1 = bta[2 * tid + 1];
  __hip_bfloat16* orow = outp + (size_t)b * PARTC * DIMC;
#pragma unroll
  for (int p = 0; p < PARTC; ++p) {
    float S = s_red[0][p] + s_red[1][p] + s_red[2][p] + s_red[3][p];
    float Q = s_red[0][PARTC + p] + s_red[1][PARTC + p] + s_red[2][PARTC + p] + s_red[3][PARTC + p];
    float mu = S * (1.f / 512.f);
    float var = Q * (1.f / 512.f) - mu * mu;
    float r = rsqrtf(var + LNEPS);
    __hip_bfloat162 hv;
    hv.x = __float2bfloat16((y0[p] - mu) * r * ga0 + bb0);
    hv.y = __float2bfloat16((y1[p] - mu) * r * ga1 + bb1);
    *(__hip_bfloat162*)(orow + p * DIMC + 2 * tid) = hv;
  }
}

// ---------------------------------------------------------------------------
// MFMA GEMM: C[M][N] = act(A[M][K] @ Bt[N][K]^T + bias)   (unchanged)
// ---------------------------------------------------------------------------
template <int BM, int BN, bool GELU>
__global__ __launch_bounds__(256) void gemm_bt(
    const __hip_bfloat16* __restrict__ A,
    const __hip_bfloat16* __restrict__ Bt,
    const float* __restrict__ bias,
    void* __restrict__ Cv,
    int M, int N, int K)
{
  constexpr int BK = 64;
  constexpr int LDT = BK + 16; // 80 bf16 = 160B row stride
  __shared__ __align__(16) unsigned short Al[BM][LDT];
  __shared__ __align__(16) unsigned short Bl[BN][LDT];

  const int tid = threadIdx.x;
  const int w = tid >> 6, lane = tid & 63;
  const int wr = w >> 1, wc = w & 1;
  const int tm = blockIdx.y * BM, tn = blockIdx.x * BN;
  constexpr int FM = BM / 32, FN = BN / 32;

  f32x4 acc[FM][FN];
#pragma unroll
  for (int m = 0; m < FM; ++m)
#pragma unroll
    for (int n = 0; n < FN; ++n) acc[m][n] = (f32x4){0.f, 0.f, 0.f, 0.f};

  const int srow = tid >> 3;        // 0..31
  const int scol = (tid & 7) * 8;   // element offset in K

  for (int k0 = 0; k0 < K; k0 += BK) {
    __syncthreads();
#pragma unroll
    for (int r = 0; r < BM / 32; ++r) {
      int row = r * 32 + srow;
      *(int4*)(&Al[row][scol]) =
          *(const int4*)(A + (size_t)(tm + row) * K + k0 + scol);
    }
#pragma unroll
    for (int r = 0; r < BN / 32; ++r) {
      int row = r * 32 + srow;
      *(int4*)(&Bl[row][scol]) =
          *(const int4*)(Bt + (size_t)(tn + row) * K + k0 + scol);
    }
    __syncthreads();

#pragma unroll
    for (int kk = 0; kk < 2; ++kk) {
      const int ko = kk * 32 + (lane >> 4) * 8;
      bf16x8 af[FM], bfr[FN];
#pragma unroll
      for (int m = 0; m < FM; ++m)
        af[m] = *(const bf16x8*)(&Al[wr * (BM / 2) + m * 16 + (lane & 15)][ko]);
#pragma unroll
      for (int n = 0; n < FN; ++n)
        bfr[n] = *(const bf16x8*)(&Bl[wc * (BN / 2) + n * 16 + (lane & 15)][ko]);
#pragma unroll
      for (int m = 0; m < FM; ++m)
#pragma unroll
        for (int n = 0; n < FN; ++n)
          acc[m][n] = __builtin_amdgcn_mfma_f32_16x16x32_bf16(
              af[m], bfr[n], acc[m][n], 0, 0, 0);
    }
  }

  // Epilogue: C/D layout col = lane&15, row = (lane>>4)*4 + r  [m89-verified]
  const int cl = lane & 15, rg = (lane >> 4) * 4;
#pragma unroll
  for (int m = 0; m < FM; ++m) {
#pragma unroll
    for (int n = 0; n < FN; ++n) {
      int col = tn + wc * (BN / 2) + n * 16 + cl;
      float bv = bias[col];
#pragma unroll
      for (int r = 0; r < 4; ++r) {
        int row = tm + wr * (BM / 2) + m * 16 + rg + r;
        float v = acc[m][n][r] + bv;
        if (GELU) {
          v = 0.5f * v * (1.f + erff(v * 0.7071067811865476f));
          ((__hip_bfloat16*)Cv)[(size_t)row * N + col] = __float2bfloat16(v);
        } else {
          ((float*)Cv)[(size_t)row * N + col] = v;
        }
      }
    }
  }
}

// ---------------------------------------------------------------------------
extern "C" void kernel_launch(void* const* d_in, const int* in_sizes, int n_in,
                              void* d_out, int out_size, void* d_ws, size_t ws_size,
                              hipStream_t stream)
{
  const float* x   = (const float*)d_in[0];
  const float* pt  = (const float*)d_in[1];
  const float* g   = (const float*)d_in[2];
  const float* bta = (const float*)d_in[3];
  const float* W1  = (const float*)d_in[4];
  const float* b1  = (const float*)d_in[5];
  const float* W2  = (const float*)d_in[6];
  const float* b2  = (const float*)d_in[7];
  float* outp = (float*)d_out;

  char* ws = (char*)d_ws;
  __hip_bfloat16* W1T = (__hip_bfloat16*)(ws);                    // 2048x512  bf16 (2 MB)
  __hip_bfloat16* W2T = (__hip_bfloat16*)(ws + 2097152);          // 512x2048  bf16 (2 MB)
  __hip_bfloat16* LNO = (__hip_bfloat16*)(ws + 4194304);          // 6144x512  bf16 (6 MB)
  __hip_bfloat16* H   = (__hip_bfloat16*)(ws + 10485760);         // 6144x2048 bf16 (25 MB)

  // K0: W1 (512x2048) -> W1T (2048x512); W2 (2048x512) -> W2T (512x2048)
  transpose_f32_bf16<<<dim3(2048 / 32, 512 / 32), dim3(32, 8), 0, stream>>>(W1, W1T, 512, 2048);
  transpose_f32_bf16<<<dim3(512 / 32, 2048 / 32), dim3(32, 8), 0, stream>>>(W2, W2T, 2048, 512);

  // S4: single-pass fused attention + LN -> LNO (x loads non-temporal)
  attn_ln_k<<<1024, 256, 0, stream>>>(x, pt, g, bta, LNO);

  // K2: h = gelu(LNO @ W1 + b1) -> H (bf16)
  gemm_bt<128, 128, true><<<dim3(2048 / 128, 6144 / 128), 256, 0, stream>>>(
      LNO, W1T, b1, (void*)H, 6144, 2048, 512);

  // K3: out = H @ W2 + b2 -> d_out (f32)  — BM=128: 16 MFMAs/K-step
  gemm_bt<128, 64, false><<<dim3(512 / 64, 6144 / 128), 256, 0, stream>>>(
      H, W2T, b2, (void*)outp, 6144, 512, 2048);
}